// Round 10
// baseline (318.286 us; speedup 1.0000x reference)
//
#include <hip/hip_runtime.h>
#include <hip/hip_bf16.h>

// GATv2Conv: N=100000, E=1000000, D_IN=128, D_OUT=64, D_EDGE=11
// heads=1, add_self_loops fill='mean', negative_slope=0.2
//
// R15: persistent + software-pipelined fused kernel.
// Ledger (H ~= 63us fixed harness overhead fitted across R13/R14):
//   gemm_place ~103, fused ~105, memset ~2 -> controllable ~210us.
// Fused per-node chain: rowload(~700cy) -> shfl -> gathers(~600cy) ->
// consume(~1300cy VALU). Row/cnt/xr/xl loads are address-predictable ->
// persistent groups (2048 blk x 8 groups, ~6 nodes each) prefetch node
// n+stride while processing node n (+~8 VGPR). Kills the rowload leg.
// k_gemm_place kept EXACTLY as R14: if fused drops below it, it finally
// surfaces in top-5 and we get its first-ever counters.
// Predicted: fused_pp 80-92 (VALU 44->55%), gemm_place ~103 visible,
// total ~250-260. Falsifier: fused unchanged -> inter-node latency was
// already hidden; next lever = attr bf16 pack / MFMA ev.

#define NN 100000
#define EE 1000000
#define DI 128
#define DO 64
#define DE 11
#define NEG 0.2f
#define NT64 1563     // 64-row tiles
#define NGEMM 512     // persistent gemm blocks
#define NPLACE 512    // persistent place blocks
#define NFB 2048      // persistent fused blocks (x8 groups = 16384 groups)
#define ROWCAP 16
#define OVCAP 64

typedef __attribute__((ext_vector_type(8))) short short8;
typedef __attribute__((ext_vector_type(4))) float f32x4;

// ---- workspace layout (bytes) ----
#define XRB_B   ((size_t)0)            // NN*DO*2 bf16 xr
#define XLB_B   ((size_t)12800000)     // NN*DO*2 bf16 xl
#define ROW_B   ((size_t)25600000)     // NN*128: 16 {e,src} pairs per node
#define OV_B    ((size_t)38400000)     // NN*OVCAP*8 overflow pairs
#define CNT_B   ((size_t)89600000)     // NN*4 counters (memset 0)

__device__ inline float4 bf4_to_f4(uint2 r) {
  float4 f;
  f.x = __uint_as_float(r.x << 16);
  f.y = __uint_as_float(r.x & 0xFFFF0000u);
  f.z = __uint_as_float(r.y << 16);
  f.w = __uint_as_float(r.y & 0xFFFF0000u);
  return f;
}

__device__ inline short f2bfs(float v) {
  union { __hip_bfloat16 b; short s; } u;
  u.b = __float2bfloat16(v);
  return u.s;
}

// ---- co-dispatch: persistent GEMM blocks + persistent place blocks ----
__global__ __launch_bounds__(256) void k_gemm_place(
    const float* __restrict__ x, const float* __restrict__ Wl,
    const float* __restrict__ Wr, const int* __restrict__ ei,
    unsigned short* __restrict__ xlb, unsigned short* __restrict__ xrb,
    unsigned* __restrict__ cnt, uint2* __restrict__ rowp,
    uint2* __restrict__ ovp) {
  __shared__ short wldsL[8192];
  __shared__ short wldsR[8192];
  if (blockIdx.x >= NGEMM) {  // placement blocks: persistent grid-stride
    int bid = blockIdx.x - NGEMM;
    for (int e = bid * 256 + threadIdx.x; e < EE; e += NPLACE * 256) {
      unsigned src = (unsigned)ei[e];
      unsigned dst = (unsigned)ei[EE + e];
      unsigned pos = atomicAdd(&cnt[dst], 1u);
      uint2 pr; pr.x = (unsigned)e; pr.y = src;
      if (pos < ROWCAP) {
        rowp[(size_t)dst * ROWCAP + pos] = pr;
      } else if (pos - ROWCAP < OVCAP) {
        ovp[(size_t)dst * OVCAP + (pos - ROWCAP)] = pr;
      }
    }
    return;
  }
  // B fragments pre-swizzled: [ks][nb][quad][l16][j] shorts — fill ONCE
  for (int t = threadIdx.x; t < 8192; t += 256) {
    int k = t >> 6, n = t & 63;
    int off = ((((k >> 5) * 4 + (n >> 4)) * 4 + ((k >> 3) & 3)) * 16 + (n & 15)) * 8 + (k & 7);
    wldsL[off] = f2bfs(Wl[t]);
    wldsR[off] = f2bfs(Wr[t]);
  }
  __syncthreads();

  int wave = threadIdx.x >> 6;
  int lane = threadIdx.x & 63;
  int quad = lane >> 4;
  int l16 = lane & 15;

  // persistent: grid-stride over 64-row tiles (amortize the LDS fill)
  for (int t64 = blockIdx.x; t64 < NT64; t64 += NGEMM) {
    int m0 = (t64 * 4 + wave) * 16;
    int row = m0 + l16;
    bool rowok = row < NN;

    f32x4 accL[4], accR[4];
#pragma unroll
    for (int nb = 0; nb < 4; ++nb) {
      accL[nb] = (f32x4){0.f, 0.f, 0.f, 0.f};
      accR[nb] = (f32x4){0.f, 0.f, 0.f, 0.f};
    }
#pragma unroll
    for (int ks = 0; ks < 4; ++ks) {
      short8 a;
      if (rowok) {
        const float* xp = x + (size_t)row * DI + ks * 32 + quad * 8;
        float4 v0 = *(const float4*)xp;
        float4 v1 = *(const float4*)(xp + 4);
        a[0] = f2bfs(v0.x); a[1] = f2bfs(v0.y); a[2] = f2bfs(v0.z); a[3] = f2bfs(v0.w);
        a[4] = f2bfs(v1.x); a[5] = f2bfs(v1.y); a[6] = f2bfs(v1.z); a[7] = f2bfs(v1.w);
      } else {
#pragma unroll
        for (int j = 0; j < 8; ++j) a[j] = 0;
      }
#pragma unroll
      for (int nb = 0; nb < 4; ++nb) {
        int off = (((ks * 4 + nb) * 4 + quad) * 16 + l16) * 8;
        short8 bl = *(const short8*)(wldsL + off);
        short8 br = *(const short8*)(wldsR + off);
        accL[nb] = __builtin_amdgcn_mfma_f32_16x16x32_bf16(a, bl, accL[nb], 0, 0, 0);
        accR[nb] = __builtin_amdgcn_mfma_f32_16x16x32_bf16(a, br, accR[nb], 0, 0, 0);
      }
    }
    // D layout: row = quad*4 + reg, col = l16 (m89-verified)
#pragma unroll
    for (int reg = 0; reg < 4; ++reg) {
      int r = m0 + quad * 4 + reg;
      if (r < NN) {
        size_t base = (size_t)r * DO + l16;
#pragma unroll
        for (int nb = 0; nb < 4; ++nb) {
          xlb[base + nb * 16] = (unsigned short)f2bfs(accL[nb][reg]);
          xrb[base + nb * 16] = (unsigned short)f2bfs(accR[nb][reg]);
        }
      }
    }
  }
}

// ---- persistent fused: prefetch next node's {cnt,row,xr,xl} ----
__global__ __launch_bounds__(128) void k_fused_pp(
    const unsigned short* __restrict__ xlb, const unsigned short* __restrict__ xrb,
    const uint2* __restrict__ rowp, const uint2* __restrict__ ovp,
    const unsigned* __restrict__ cnt, const float* __restrict__ attr,
    const float* __restrict__ We, const float* __restrict__ att,
    float* __restrict__ out) {
  int g = threadIdx.x & 15;
  int grp = threadIdx.x >> 4;       // 0..7
  int k0 = g * 4;
  const int gstride = NFB * 8;      // 16384 groups

  float4 W[DE];
#pragma unroll
  for (int j = 0; j < DE; ++j) W[j] = *(const float4*)(We + j * DO + k0);
  const float4 a4 = *(const float4*)(att + k0);

  int i = blockIdx.x * 8 + grp;     // first node (always < NN)

  // prologue prefetch
  unsigned d_nx = cnt[i];
  uint2 p_nx = rowp[(size_t)i * ROWCAP + g];
  uint2 xr_nx = *(const uint2*)(xrb + (size_t)i * DO + k0);
  uint2 xl_nx = *(const uint2*)(xlb + (size_t)i * DO + k0);

  while (i < NN) {
    // rotate prefetched state in
    unsigned d = d_nx;
    uint2 p = p_nx;
    float4 xri = bf4_to_f4(xr_nx);
    float4 xli = bf4_to_f4(xl_nx);
    int inext = i + gstride;
    if (inext < NN) {  // issue next node's loads; consumed after this node
      d_nx = cnt[inext];
      p_nx = rowp[(size_t)inext * ROWCAP + g];
      xr_nx = *(const uint2*)(xrb + (size_t)inext * DO + k0);
      xl_nx = *(const uint2*)(xlb + (size_t)inext * DO + k0);
    }

    unsigned drow = d < ROWCAP ? d : ROWCAP;
    float4 acc = {0.f, 0.f, 0.f, 0.f};
    float den = 0.f;
    float asum = 0.f;  // lane g (g<11): sum of attr[g] over incoming edges

    // ---- main path: pairs in registers, distribute via shfl ----
    for (unsigned c = 0; c < drow; c += 8) {
      unsigned rem = drow - c;
      if (rem > 8) rem = 8;
#define LP(ii)                                                              \
      unsigned E##ii = 0u, S##ii = 0u;                                      \
      if ((unsigned)ii < rem) {                                             \
        E##ii = __shfl(p.x, (int)(c + ii), 16);                             \
        S##ii = __shfl(p.y, (int)(c + ii), 16);                             \
      }
      LP(0) LP(1) LP(2) LP(3) LP(4) LP(5) LP(6) LP(7)
#undef LP
#define LA(ii)                                                              \
      float A##ii = 0.f;                                                    \
      if ((unsigned)ii < rem && g < DE)                                     \
        A##ii = attr[(size_t)E##ii * DE + g];
      LA(0) LA(1) LA(2) LA(3) LA(4) LA(5) LA(6) LA(7)
#undef LA
#define LR(ii)                                                              \
      uint2 R##ii = {0u, 0u};                                               \
      if ((unsigned)ii < rem) R##ii = *(const uint2*)(xlb + (size_t)S##ii * DO + k0);
      LR(0) LR(1) LR(2) LR(3) LR(4) LR(5) LR(6) LR(7)
#undef LR
#define CS(ii)                                                              \
      if ((unsigned)ii < rem) {                                             \
        float4 vl = bf4_to_f4(R##ii);                                       \
        float4 ev = {0.f, 0.f, 0.f, 0.f};                                   \
        _Pragma("unroll")                                                   \
        for (int j = 0; j < DE; ++j) {                                      \
          float a = __shfl(A##ii, j, 16);                                   \
          ev.x += a * W[j].x; ev.y += a * W[j].y;                           \
          ev.z += a * W[j].z; ev.w += a * W[j].w;                           \
        }                                                                   \
        float4 m;                                                           \
        m.x = vl.x + xri.x + ev.x; m.y = vl.y + xri.y + ev.y;               \
        m.z = vl.z + xri.z + ev.z; m.w = vl.w + xri.w + ev.w;               \
        m.x = m.x >= 0.f ? m.x : NEG * m.x;                                 \
        m.y = m.y >= 0.f ? m.y : NEG * m.y;                                 \
        m.z = m.z >= 0.f ? m.z : NEG * m.z;                                 \
        m.w = m.w >= 0.f ? m.w : NEG * m.w;                                 \
        float s = m.x * a4.x + m.y * a4.y + m.z * a4.z + m.w * a4.w;        \
        s += __shfl_xor(s, 1); s += __shfl_xor(s, 2);                       \
        s += __shfl_xor(s, 4); s += __shfl_xor(s, 8);                       \
        float ex = __expf(s);                                               \
        acc.x += ex * vl.x; acc.y += ex * vl.y;                             \
        acc.z += ex * vl.z; acc.w += ex * vl.w;                             \
        den += ex;                                                          \
        asum += A##ii;                                                      \
      }
      CS(0) CS(1) CS(2) CS(3) CS(4) CS(5) CS(6) CS(7)
#undef CS
    }

    // ---- rare overflow path (d > 16) ----
    if (d > ROWCAP) {
      unsigned dtot = d < (ROWCAP + OVCAP) ? d : (ROWCAP + OVCAP);
      for (unsigned c = ROWCAP; c < dtot; c += 8) {
        unsigned rem = dtot - c;
        if (rem > 8) rem = 8;
        size_t sp = (size_t)i * OVCAP + (c - ROWCAP);
#define LQ(ii)                                                              \
        unsigned E##ii = 0u, S##ii = 0u;                                    \
        if ((unsigned)ii < rem) {                                           \
          uint2 q = ovp[sp + ii];                                           \
          E##ii = q.x; S##ii = q.y;                                         \
        }
        LQ(0) LQ(1) LQ(2) LQ(3) LQ(4) LQ(5) LQ(6) LQ(7)
#undef LQ
#define LA(ii)                                                              \
        float A##ii = 0.f;                                                  \
        if ((unsigned)ii < rem && g < DE)                                   \
          A##ii = attr[(size_t)E##ii * DE + g];
        LA(0) LA(1) LA(2) LA(3) LA(4) LA(5) LA(6) LA(7)
#undef LA
#define LR(ii)                                                              \
        uint2 R##ii = {0u, 0u};                                             \
        if ((unsigned)ii < rem) R##ii = *(const uint2*)(xlb + (size_t)S##ii * DO + k0);
        LR(0) LR(1) LR(2) LR(3) LR(4) LR(5) LR(6) LR(7)
#undef LR
#define CS(ii)                                                              \
        if ((unsigned)ii < rem) {                                           \
          float4 vl = bf4_to_f4(R##ii);                                     \
          float4 ev = {0.f, 0.f, 0.f, 0.f};                                 \
          _Pragma("unroll")                                                 \
          for (int j = 0; j < DE; ++j) {                                    \
            float a = __shfl(A##ii, j, 16);                                 \
            ev.x += a * W[j].x; ev.y += a * W[j].y;                         \
            ev.z += a * W[j].z; ev.w += a * W[j].w;                         \
          }                                                                 \
          float4 m;                                                         \
          m.x = vl.x + xri.x + ev.x; m.y = vl.y + xri.y + ev.y;             \
          m.z = vl.z + xri.z + ev.z; m.w = vl.w + xri.w + ev.w;             \
          m.x = m.x >= 0.f ? m.x : NEG * m.x;                               \
          m.y = m.y >= 0.f ? m.y : NEG * m.y;                               \
          m.z = m.z >= 0.f ? m.z : NEG * m.z;                               \
          m.w = m.w >= 0.f ? m.w : NEG * m.w;                               \
          float s = m.x * a4.x + m.y * a4.y + m.z * a4.z + m.w * a4.w;      \
          s += __shfl_xor(s, 1); s += __shfl_xor(s, 2);                     \
          s += __shfl_xor(s, 4); s += __shfl_xor(s, 8);                     \
          float ex = __expf(s);                                             \
          acc.x += ex * vl.x; acc.y += ex * vl.y;                           \
          acc.z += ex * vl.z; acc.w += ex * vl.w;                           \
          den += ex;                                                        \
          asum += A##ii;                                                    \
        }
        CS(0) CS(1) CS(2) CS(3) CS(4) CS(5) CS(6) CS(7)
#undef CS
      }
    }

    // self-loop: mean(attr)@We (linearity), shfl-broadcast from asum lanes
    float la = asum / fmaxf((float)d, 1.0f);
    float4 evs = {0.f, 0.f, 0.f, 0.f};
#pragma unroll
    for (int j = 0; j < DE; ++j) {
      float aj = __shfl(la, j, 16);
      evs.x += aj * W[j].x; evs.y += aj * W[j].y;
      evs.z += aj * W[j].z; evs.w += aj * W[j].w;
    }
    float4 m;
    m.x = xli.x + xri.x + evs.x;
    m.y = xli.y + xri.y + evs.y;
    m.z = xli.z + xri.z + evs.z;
    m.w = xli.w + xri.w + evs.w;
    m.x = m.x >= 0.f ? m.x : NEG * m.x;
    m.y = m.y >= 0.f ? m.y : NEG * m.y;
    m.z = m.z >= 0.f ? m.z : NEG * m.z;
    m.w = m.w >= 0.f ? m.w : NEG * m.w;
    float s = m.x * a4.x + m.y * a4.y + m.z * a4.z + m.w * a4.w;
    s += __shfl_xor(s, 1); s += __shfl_xor(s, 2);
    s += __shfl_xor(s, 4); s += __shfl_xor(s, 8);
    float exs = __expf(s);
    float inv = 1.0f / (den + exs);
    float4 o;
    o.x = (acc.x + exs * xli.x) * inv;
    o.y = (acc.y + exs * xli.y) * inv;
    o.z = (acc.z + exs * xli.z) * inv;
    o.w = (acc.w + exs * xli.w) * inv;
    *(float4*)(out + (size_t)i * DO + k0) = o;

    i = inext;
  }
}

extern "C" void kernel_launch(void* const* d_in, const int* in_sizes, int n_in,
                              void* d_out, int out_size, void* d_ws, size_t ws_size,
                              hipStream_t stream) {
  const float* x    = (const float*)d_in[0];
  const int*   ei   = (const int*)d_in[1];
  const float* attr = (const float*)d_in[2];
  const float* Wl   = (const float*)d_in[3];
  const float* Wr   = (const float*)d_in[4];
  const float* We   = (const float*)d_in[5];
  const float* att  = (const float*)d_in[6];
  float* out = (float*)d_out;

  char* ws = (char*)d_ws;
  unsigned short* xrb  = (unsigned short*)(ws + XRB_B);
  unsigned short* xlb  = (unsigned short*)(ws + XLB_B);
  uint2*          rowp = (uint2*)(ws + ROW_B);
  uint2*          ovp  = (uint2*)(ws + OV_B);
  unsigned*       cnt  = (unsigned*)(ws + CNT_B);

  hipMemsetAsync(cnt, 0, (size_t)NN * 4, stream);

  k_gemm_place<<<NGEMM + NPLACE, 256, 0, stream>>>(
      x, Wl, Wr, ei, xlb, xrb, cnt, rowp, ovp);
  k_fused_pp<<<NFB, 128, 0, stream>>>(
      xlb, xrb, rowp, ovp, cnt, attr, We, att, out);
}

// Round 11
// 306.399 us; speedup vs baseline: 1.0388x; 1.0388x over previous
//
#include <hip/hip_runtime.h>
#include <hip/hip_bf16.h>

// GATv2Conv: N=100000, E=1000000, D_IN=128, D_OUT=64, D_EDGE=11
// heads=1, add_self_loops fill='mean', negative_slope=0.2
//
// R16: XCD-partitioned placement + revert fused to R14.
// Evidence (R15): k_gemm_place first counters: 121us, MfmaUtil 1%,
// VALUBusy 3.3% (both pipes IDLE), WRITE 87MB vs ~40 expected -> the
// +47MB = cross-XCD coherence ping-pong on cnt/rowp lines (each dst's
// 128-B row written from ~8 XCDs => ~7 ownership migrations x writeback).
// Fix: placement block bid handles ONLY dst in XCD (bid&7)'s range
// [xcd*12500,(xcd+1)*12500), scanning the full dst stream (4MB, L3-shared
// across the 8 scans). All cnt/rowp traffic becomes XCD-local.
// blockIdx%8~XCD is a dispatch heuristic (m09); wrong mapping = no gain,
// never wrong results. R15's fused prefetch REVERTED (105->121 regression:
// TLP already hid inter-node latency; prefetch only cost VGPR+occupancy).
// Predicted: gemm_place 121->45-65 (WRITE ~42MB), fused ~105, total
// ~215-240. Falsifier: gemm_place unchanged -> split dispatch next round.

#define NN 100000
#define EE 1000000
#define DI 128
#define DO 64
#define DE 11
#define NEG 0.2f
#define NT64 1563     // 64-row tiles
#define NGEMM 512     // persistent gemm blocks
#define NPLACE 512    // persistent place blocks (64 per XCD)
#define ROWCAP 16
#define OVCAP 64

typedef __attribute__((ext_vector_type(8))) short short8;
typedef __attribute__((ext_vector_type(4))) float f32x4;

// ---- workspace layout (bytes) ----
#define XRB_B   ((size_t)0)            // NN*DO*2 bf16 xr
#define XLB_B   ((size_t)12800000)     // NN*DO*2 bf16 xl
#define ROW_B   ((size_t)25600000)     // NN*128: 16 {e,src} pairs per node
#define OV_B    ((size_t)38400000)     // NN*OVCAP*8 overflow pairs
#define CNT_B   ((size_t)89600000)     // NN*4 counters (memset 0)

__device__ inline float4 bf4_to_f4(uint2 r) {
  float4 f;
  f.x = __uint_as_float(r.x << 16);
  f.y = __uint_as_float(r.x & 0xFFFF0000u);
  f.z = __uint_as_float(r.y << 16);
  f.w = __uint_as_float(r.y & 0xFFFF0000u);
  return f;
}

__device__ inline short f2bfs(float v) {
  union { __hip_bfloat16 b; short s; } u;
  u.b = __float2bfloat16(v);
  return u.s;
}

// ---- co-dispatch: persistent GEMM blocks + XCD-partitioned place blocks ----
__global__ __launch_bounds__(256) void k_gemm_place(
    const float* __restrict__ x, const float* __restrict__ Wl,
    const float* __restrict__ Wr, const int* __restrict__ ei,
    unsigned short* __restrict__ xlb, unsigned short* __restrict__ xrb,
    unsigned* __restrict__ cnt, uint2* __restrict__ rowp,
    uint2* __restrict__ ovp) {
  __shared__ short wldsL[8192];
  __shared__ short wldsR[8192];
  if (blockIdx.x >= NGEMM) {  // placement: XCD-local dst partition
    int bid = blockIdx.x - NGEMM;     // 0..NPLACE-1; grid offset 512 = 0 mod 8
    int xcd = bid & 7;                // heuristic XCD id (round-robin dispatch)
    int sub = bid >> 3;               // 0..63 within the XCD's group
    unsigned lo = (unsigned)xcd * (NN / 8);
    unsigned hi = lo + (NN / 8);
    const int estride = (NPLACE >> 3) * 256;   // 16384
    for (int e = sub * 256 + threadIdx.x; e < EE; e += estride) {
      unsigned dst = (unsigned)ei[EE + e];
      if (dst >= lo && dst < hi) {    // ~1/8 of edges owned
        unsigned src = (unsigned)ei[e];
        unsigned pos = atomicAdd(&cnt[dst], 1u);   // XCD-local line
        uint2 pr; pr.x = (unsigned)e; pr.y = src;
        if (pos < ROWCAP) {
          rowp[(size_t)dst * ROWCAP + pos] = pr;   // XCD-local line
        } else if (pos - ROWCAP < OVCAP) {
          ovp[(size_t)dst * OVCAP + (pos - ROWCAP)] = pr;
        }
      }
    }
    return;
  }
  // B fragments pre-swizzled: [ks][nb][quad][l16][j] shorts — fill ONCE
  for (int t = threadIdx.x; t < 8192; t += 256) {
    int k = t >> 6, n = t & 63;
    int off = ((((k >> 5) * 4 + (n >> 4)) * 4 + ((k >> 3) & 3)) * 16 + (n & 15)) * 8 + (k & 7);
    wldsL[off] = f2bfs(Wl[t]);
    wldsR[off] = f2bfs(Wr[t]);
  }
  __syncthreads();

  int wave = threadIdx.x >> 6;
  int lane = threadIdx.x & 63;
  int quad = lane >> 4;
  int l16 = lane & 15;

  // persistent: grid-stride over 64-row tiles (amortize the LDS fill)
  for (int t64 = blockIdx.x; t64 < NT64; t64 += NGEMM) {
    int m0 = (t64 * 4 + wave) * 16;
    int row = m0 + l16;
    bool rowok = row < NN;

    f32x4 accL[4], accR[4];
#pragma unroll
    for (int nb = 0; nb < 4; ++nb) {
      accL[nb] = (f32x4){0.f, 0.f, 0.f, 0.f};
      accR[nb] = (f32x4){0.f, 0.f, 0.f, 0.f};
    }
#pragma unroll
    for (int ks = 0; ks < 4; ++ks) {
      short8 a;
      if (rowok) {
        const float* xp = x + (size_t)row * DI + ks * 32 + quad * 8;
        float4 v0 = *(const float4*)xp;
        float4 v1 = *(const float4*)(xp + 4);
        a[0] = f2bfs(v0.x); a[1] = f2bfs(v0.y); a[2] = f2bfs(v0.z); a[3] = f2bfs(v0.w);
        a[4] = f2bfs(v1.x); a[5] = f2bfs(v1.y); a[6] = f2bfs(v1.z); a[7] = f2bfs(v1.w);
      } else {
#pragma unroll
        for (int j = 0; j < 8; ++j) a[j] = 0;
      }
#pragma unroll
      for (int nb = 0; nb < 4; ++nb) {
        int off = (((ks * 4 + nb) * 4 + quad) * 16 + l16) * 8;
        short8 bl = *(const short8*)(wldsL + off);
        short8 br = *(const short8*)(wldsR + off);
        accL[nb] = __builtin_amdgcn_mfma_f32_16x16x32_bf16(a, bl, accL[nb], 0, 0, 0);
        accR[nb] = __builtin_amdgcn_mfma_f32_16x16x32_bf16(a, br, accR[nb], 0, 0, 0);
      }
    }
    // D layout: row = quad*4 + reg, col = l16 (m89-verified)
#pragma unroll
    for (int reg = 0; reg < 4; ++reg) {
      int r = m0 + quad * 4 + reg;
      if (r < NN) {
        size_t base = (size_t)r * DO + l16;
#pragma unroll
        for (int nb = 0; nb < 4; ++nb) {
          xlb[base + nb * 16] = (unsigned short)f2bfs(accL[nb][reg]);
          xrb[base + nb * 16] = (unsigned short)f2bfs(accR[nb][reg]);
        }
      }
    }
  }
}

// ---- fused: cnt load + 1 row load + shfl distribute (R14-proven, 105us) ----
__global__ __launch_bounds__(128) void k_fused_row16(
    const unsigned short* __restrict__ xlb, const unsigned short* __restrict__ xrb,
    const uint2* __restrict__ rowp, const uint2* __restrict__ ovp,
    const unsigned* __restrict__ cnt, const float* __restrict__ attr,
    const float* __restrict__ We, const float* __restrict__ att,
    float* __restrict__ out) {
  int t = blockIdx.x * 128 + threadIdx.x;
  int i = t >> 4;  // 16 lanes per dst node, 4 dims per lane
  int g = t & 15;
  if (i >= NN) return;
  int k0 = g * 4;

  float4 W[DE];
#pragma unroll
  for (int j = 0; j < DE; ++j) W[j] = *(const float4*)(We + j * DO + k0);
  const float4 a4 = *(const float4*)(att + k0);
  float4 xri = bf4_to_f4(*(const uint2*)(xrb + (size_t)i * DO + k0));
  float4 xli = bf4_to_f4(*(const uint2*)(xlb + (size_t)i * DO + k0));

  unsigned d = cnt[i];  // same addr across 16 lanes (L1 broadcast)
  // ONE coalesced 128-B row load: up to 16 {e,src} pairs
  uint2 p = rowp[(size_t)i * ROWCAP + g];
  unsigned drow = d < ROWCAP ? d : ROWCAP;

  float4 acc = {0.f, 0.f, 0.f, 0.f};
  float den = 0.f;
  float asum = 0.f;  // lane g (g<11): sum of attr[g] over incoming edges

  // ---- main path: pairs in registers, distribute via shfl ----
  for (unsigned c = 0; c < drow; c += 8) {
    unsigned rem = drow - c;
    if (rem > 8) rem = 8;
#define LP(ii)                                                              \
    unsigned E##ii = 0u, S##ii = 0u;                                        \
    if ((unsigned)ii < rem) {                                               \
      E##ii = __shfl(p.x, (int)(c + ii), 16);                               \
      S##ii = __shfl(p.y, (int)(c + ii), 16);                               \
    }
    LP(0) LP(1) LP(2) LP(3) LP(4) LP(5) LP(6) LP(7)
#undef LP
#define LA(ii)                                                              \
    float A##ii = 0.f;                                                      \
    if ((unsigned)ii < rem && g < DE)                                       \
      A##ii = attr[(size_t)E##ii * DE + g];
    LA(0) LA(1) LA(2) LA(3) LA(4) LA(5) LA(6) LA(7)
#undef LA
#define LR(ii)                                                              \
    uint2 R##ii = {0u, 0u};                                                 \
    if ((unsigned)ii < rem) R##ii = *(const uint2*)(xlb + (size_t)S##ii * DO + k0);
    LR(0) LR(1) LR(2) LR(3) LR(4) LR(5) LR(6) LR(7)
#undef LR
#define CS(ii)                                                              \
    if ((unsigned)ii < rem) {                                               \
      float4 vl = bf4_to_f4(R##ii);                                         \
      float4 ev = {0.f, 0.f, 0.f, 0.f};                                     \
      _Pragma("unroll")                                                     \
      for (int j = 0; j < DE; ++j) {                                        \
        float a = __shfl(A##ii, j, 16);                                     \
        ev.x += a * W[j].x; ev.y += a * W[j].y;                             \
        ev.z += a * W[j].z; ev.w += a * W[j].w;                             \
      }                                                                     \
      float4 m;                                                             \
      m.x = vl.x + xri.x + ev.x; m.y = vl.y + xri.y + ev.y;                 \
      m.z = vl.z + xri.z + ev.z; m.w = vl.w + xri.w + ev.w;                 \
      m.x = m.x >= 0.f ? m.x : NEG * m.x;                                   \
      m.y = m.y >= 0.f ? m.y : NEG * m.y;                                   \
      m.z = m.z >= 0.f ? m.z : NEG * m.z;                                   \
      m.w = m.w >= 0.f ? m.w : NEG * m.w;                                   \
      float s = m.x * a4.x + m.y * a4.y + m.z * a4.z + m.w * a4.w;          \
      s += __shfl_xor(s, 1); s += __shfl_xor(s, 2);                         \
      s += __shfl_xor(s, 4); s += __shfl_xor(s, 8);                         \
      float ex = __expf(s);                                                 \
      acc.x += ex * vl.x; acc.y += ex * vl.y;                               \
      acc.z += ex * vl.z; acc.w += ex * vl.w;                               \
      den += ex;                                                            \
      asum += A##ii;                                                        \
    }
    CS(0) CS(1) CS(2) CS(3) CS(4) CS(5) CS(6) CS(7)
#undef CS
  }

  // ---- rare overflow path (d > 16) ----
  if (d > ROWCAP) {
    unsigned dtot = d < (ROWCAP + OVCAP) ? d : (ROWCAP + OVCAP);
    for (unsigned c = ROWCAP; c < dtot; c += 8) {
      unsigned rem = dtot - c;
      if (rem > 8) rem = 8;
      size_t sp = (size_t)i * OVCAP + (c - ROWCAP);
#define LQ(ii)                                                              \
      unsigned E##ii = 0u, S##ii = 0u;                                      \
      if ((unsigned)ii < rem) {                                             \
        uint2 q = ovp[sp + ii];                                             \
        E##ii = q.x; S##ii = q.y;                                           \
      }
      LQ(0) LQ(1) LQ(2) LQ(3) LQ(4) LQ(5) LQ(6) LQ(7)
#undef LQ
#define LA(ii)                                                              \
      float A##ii = 0.f;                                                    \
      if ((unsigned)ii < rem && g < DE)                                     \
        A##ii = attr[(size_t)E##ii * DE + g];
      LA(0) LA(1) LA(2) LA(3) LA(4) LA(5) LA(6) LA(7)
#undef LA
#define LR(ii)                                                              \
      uint2 R##ii = {0u, 0u};                                               \
      if ((unsigned)ii < rem) R##ii = *(const uint2*)(xlb + (size_t)S##ii * DO + k0);
      LR(0) LR(1) LR(2) LR(3) LR(4) LR(5) LR(6) LR(7)
#undef LR
#define CS(ii)                                                              \
      if ((unsigned)ii < rem) {                                             \
        float4 vl = bf4_to_f4(R##ii);                                       \
        float4 ev = {0.f, 0.f, 0.f, 0.f};                                   \
        _Pragma("unroll")                                                   \
        for (int j = 0; j < DE; ++j) {                                      \
          float a = __shfl(A##ii, j, 16);                                   \
          ev.x += a * W[j].x; ev.y += a * W[j].y;                           \
          ev.z += a * W[j].z; ev.w += a * W[j].w;                           \
        }                                                                   \
        float4 m;                                                           \
        m.x = vl.x + xri.x + ev.x; m.y = vl.y + xri.y + ev.y;               \
        m.z = vl.z + xri.z + ev.z; m.w = vl.w + xri.w + ev.w;               \
        m.x = m.x >= 0.f ? m.x : NEG * m.x;                                 \
        m.y = m.y >= 0.f ? m.y : NEG * m.y;                                 \
        m.z = m.z >= 0.f ? m.z : NEG * m.z;                                 \
        m.w = m.w >= 0.f ? m.w : NEG * m.w;                                 \
        float s = m.x * a4.x + m.y * a4.y + m.z * a4.z + m.w * a4.w;        \
        s += __shfl_xor(s, 1); s += __shfl_xor(s, 2);                       \
        s += __shfl_xor(s, 4); s += __shfl_xor(s, 8);                       \
        float ex = __expf(s);                                               \
        acc.x += ex * vl.x; acc.y += ex * vl.y;                             \
        acc.z += ex * vl.z; acc.w += ex * vl.w;                             \
        den += ex;                                                          \
        asum += A##ii;                                                      \
      }
      CS(0) CS(1) CS(2) CS(3) CS(4) CS(5) CS(6) CS(7)
#undef CS
    }
  }

  // self-loop: mean(attr)@We (linearity), shfl-broadcast from asum lanes
  float la = asum / fmaxf((float)d, 1.0f);
  float4 evs = {0.f, 0.f, 0.f, 0.f};
#pragma unroll
  for (int j = 0; j < DE; ++j) {
    float aj = __shfl(la, j, 16);
    evs.x += aj * W[j].x; evs.y += aj * W[j].y;
    evs.z += aj * W[j].z; evs.w += aj * W[j].w;
  }
  float4 m;
  m.x = xli.x + xri.x + evs.x;
  m.y = xli.y + xri.y + evs.y;
  m.z = xli.z + xri.z + evs.z;
  m.w = xli.w + xri.w + evs.w;
  m.x = m.x >= 0.f ? m.x : NEG * m.x;
  m.y = m.y >= 0.f ? m.y : NEG * m.y;
  m.z = m.z >= 0.f ? m.z : NEG * m.z;
  m.w = m.w >= 0.f ? m.w : NEG * m.w;
  float s = m.x * a4.x + m.y * a4.y + m.z * a4.z + m.w * a4.w;
  s += __shfl_xor(s, 1); s += __shfl_xor(s, 2);
  s += __shfl_xor(s, 4); s += __shfl_xor(s, 8);
  float exs = __expf(s);
  float inv = 1.0f / (den + exs);
  float4 o;
  o.x = (acc.x + exs * xli.x) * inv;
  o.y = (acc.y + exs * xli.y) * inv;
  o.z = (acc.z + exs * xli.z) * inv;
  o.w = (acc.w + exs * xli.w) * inv;
  *(float4*)(out + (size_t)i * DO + k0) = o;
}

extern "C" void kernel_launch(void* const* d_in, const int* in_sizes, int n_in,
                              void* d_out, int out_size, void* d_ws, size_t ws_size,
                              hipStream_t stream) {
  const float* x    = (const float*)d_in[0];
  const int*   ei   = (const int*)d_in[1];
  const float* attr = (const float*)d_in[2];
  const float* Wl   = (const float*)d_in[3];
  const float* Wr   = (const float*)d_in[4];
  const float* We   = (const float*)d_in[5];
  const float* att  = (const float*)d_in[6];
  float* out = (float*)d_out;

  char* ws = (char*)d_ws;
  unsigned short* xrb  = (unsigned short*)(ws + XRB_B);
  unsigned short* xlb  = (unsigned short*)(ws + XLB_B);
  uint2*          rowp = (uint2*)(ws + ROW_B);
  uint2*          ovp  = (uint2*)(ws + OV_B);
  unsigned*       cnt  = (unsigned*)(ws + CNT_B);

  hipMemsetAsync(cnt, 0, (size_t)NN * 4, stream);

  k_gemm_place<<<NGEMM + NPLACE, 256, 0, stream>>>(
      x, Wl, Wr, ei, xlb, xrb, cnt, rowp, ovp);
  k_fused_row16<<<(NN * 16 + 127) / 128, 128, 0, stream>>>(
      xlb, xrb, rowp, ovp, cnt, attr, We, att, out);
}

// Round 12
// 284.257 us; speedup vs baseline: 1.1197x; 1.0779x over previous
//
#include <hip/hip_runtime.h>
#include <hip/hip_bf16.h>

// GATv2Conv: N=100000, E=1000000, D_IN=128, D_OUT=64, D_EDGE=11
// heads=1, add_self_loops fill='mean', negative_slope=0.2
//
// R17: unify gemm+place phases in persistent blocks + 4-edge vectorized
// placement. Evidence: R15/R16 gemm_place at 21% occupancy, MfmaUtil 1%,
// VALU 6% — half-grid phase split leaves the machine idle in each phase's
// tail; placement = 1 dependent load->atomic->store chain per thread (no
// MLP). R16's XCD partition REVERTED (8x scan cost > ping-pong savings;
// R14 total 274.5 beat R16's 306.4).
//  - ALL 1024 blocks: GEMM tiles (grid-stride) THEN placement (no sync
//    needed, disjoint outputs). Each phase gets the full machine.
//  - placement: 4 edges/thread via int4 loads; 4 independent atomic+store
//    chains in flight (~4x MLP on the latency critical path).
//  - fused: R14 k_fused_row16 verbatim (105us proven).
// Predicted: gemm_place 65-85 (occ ~40%, FETCH ~30, WRITE ~85), fused
// ~105, total ~235-255. Falsifier: gemm_place>=100 -> atomic/L2
// throughput wall -> wave-level dst dedup next.

#define NN 100000
#define EE 1000000
#define DI 128
#define DO 64
#define DE 11
#define NEG 0.2f
#define NT64 1563     // 64-row tiles
#define NBLK 1024     // unified persistent blocks
#define ROWCAP 16
#define OVCAP 64

typedef __attribute__((ext_vector_type(8))) short short8;
typedef __attribute__((ext_vector_type(4))) float f32x4;

// ---- workspace layout (bytes) ----
#define XRB_B   ((size_t)0)            // NN*DO*2 bf16 xr
#define XLB_B   ((size_t)12800000)     // NN*DO*2 bf16 xl
#define ROW_B   ((size_t)25600000)     // NN*128: 16 {e,src} pairs per node
#define OV_B    ((size_t)38400000)     // NN*OVCAP*8 overflow pairs
#define CNT_B   ((size_t)89600000)     // NN*4 counters (memset 0)

__device__ inline float4 bf4_to_f4(uint2 r) {
  float4 f;
  f.x = __uint_as_float(r.x << 16);
  f.y = __uint_as_float(r.x & 0xFFFF0000u);
  f.z = __uint_as_float(r.y << 16);
  f.w = __uint_as_float(r.y & 0xFFFF0000u);
  return f;
}

__device__ inline short f2bfs(float v) {
  union { __hip_bfloat16 b; short s; } u;
  u.b = __float2bfloat16(v);
  return u.s;
}

// ---- unified persistent: GEMM phase then placement phase, all blocks ----
__global__ __launch_bounds__(256) void k_gemm_place(
    const float* __restrict__ x, const float* __restrict__ Wl,
    const float* __restrict__ Wr, const int* __restrict__ ei,
    unsigned short* __restrict__ xlb, unsigned short* __restrict__ xrb,
    unsigned* __restrict__ cnt, uint2* __restrict__ rowp,
    uint2* __restrict__ ovp) {
  __shared__ short wldsL[8192];
  __shared__ short wldsR[8192];
  // B fragments pre-swizzled: [ks][nb][quad][l16][j] shorts — fill once
  for (int t = threadIdx.x; t < 8192; t += 256) {
    int k = t >> 6, n = t & 63;
    int off = ((((k >> 5) * 4 + (n >> 4)) * 4 + ((k >> 3) & 3)) * 16 + (n & 15)) * 8 + (k & 7);
    wldsL[off] = f2bfs(Wl[t]);
    wldsR[off] = f2bfs(Wr[t]);
  }
  __syncthreads();

  int wave = threadIdx.x >> 6;
  int lane = threadIdx.x & 63;
  int quad = lane >> 4;
  int l16 = lane & 15;

  // ---- phase 1: GEMM, grid-stride over 64-row tiles ----
  for (int t64 = blockIdx.x; t64 < NT64; t64 += NBLK) {
    int m0 = (t64 * 4 + wave) * 16;
    int row = m0 + l16;
    bool rowok = row < NN;

    f32x4 accL[4], accR[4];
#pragma unroll
    for (int nb = 0; nb < 4; ++nb) {
      accL[nb] = (f32x4){0.f, 0.f, 0.f, 0.f};
      accR[nb] = (f32x4){0.f, 0.f, 0.f, 0.f};
    }
#pragma unroll
    for (int ks = 0; ks < 4; ++ks) {
      short8 a;
      if (rowok) {
        const float* xp = x + (size_t)row * DI + ks * 32 + quad * 8;
        float4 v0 = *(const float4*)xp;
        float4 v1 = *(const float4*)(xp + 4);
        a[0] = f2bfs(v0.x); a[1] = f2bfs(v0.y); a[2] = f2bfs(v0.z); a[3] = f2bfs(v0.w);
        a[4] = f2bfs(v1.x); a[5] = f2bfs(v1.y); a[6] = f2bfs(v1.z); a[7] = f2bfs(v1.w);
      } else {
#pragma unroll
        for (int j = 0; j < 8; ++j) a[j] = 0;
      }
#pragma unroll
      for (int nb = 0; nb < 4; ++nb) {
        int off = (((ks * 4 + nb) * 4 + quad) * 16 + l16) * 8;
        short8 bl = *(const short8*)(wldsL + off);
        short8 br = *(const short8*)(wldsR + off);
        accL[nb] = __builtin_amdgcn_mfma_f32_16x16x32_bf16(a, bl, accL[nb], 0, 0, 0);
        accR[nb] = __builtin_amdgcn_mfma_f32_16x16x32_bf16(a, br, accR[nb], 0, 0, 0);
      }
    }
    // D layout: row = quad*4 + reg, col = l16 (m89-verified)
#pragma unroll
    for (int reg = 0; reg < 4; ++reg) {
      int r = m0 + quad * 4 + reg;
      if (r < NN) {
        size_t base = (size_t)r * DO + l16;
#pragma unroll
        for (int nb = 0; nb < 4; ++nb) {
          xlb[base + nb * 16] = (unsigned short)f2bfs(accL[nb][reg]);
          xrb[base + nb * 16] = (unsigned short)f2bfs(accR[nb][reg]);
        }
      }
    }
  }

  // ---- phase 2: placement, 4 edges/thread via int4 (MLP x4) ----
  {
    int e0 = (blockIdx.x * 256 + threadIdx.x) * 4;   // one int4 group each
    if (e0 < EE) {
      int4 s4 = *(const int4*)(ei + e0);
      int4 d4 = *(const int4*)(ei + EE + e0);
      // 4 independent atomic+store chains — hardware overlaps them
      unsigned p0 = atomicAdd(&cnt[(unsigned)d4.x], 1u);
      unsigned p1 = atomicAdd(&cnt[(unsigned)d4.y], 1u);
      unsigned p2 = atomicAdd(&cnt[(unsigned)d4.z], 1u);
      unsigned p3 = atomicAdd(&cnt[(unsigned)d4.w], 1u);
#define PUT(pp, dd, ee, ss)                                                 \
      {                                                                     \
        uint2 pr; pr.x = (unsigned)(ee); pr.y = (unsigned)(ss);             \
        if ((pp) < ROWCAP) {                                                \
          rowp[(size_t)(unsigned)(dd) * ROWCAP + (pp)] = pr;                \
        } else if ((pp) - ROWCAP < OVCAP) {                                 \
          ovp[(size_t)(unsigned)(dd) * OVCAP + ((pp) - ROWCAP)] = pr;       \
        }                                                                   \
      }
      PUT(p0, d4.x, e0 + 0, s4.x)
      PUT(p1, d4.y, e0 + 1, s4.y)
      PUT(p2, d4.z, e0 + 2, s4.z)
      PUT(p3, d4.w, e0 + 3, s4.w)
#undef PUT
    }
  }
}

// ---- fused: cnt load + 1 row load + shfl distribute (R14-proven, 105us) ----
__global__ __launch_bounds__(128) void k_fused_row16(
    const unsigned short* __restrict__ xlb, const unsigned short* __restrict__ xrb,
    const uint2* __restrict__ rowp, const uint2* __restrict__ ovp,
    const unsigned* __restrict__ cnt, const float* __restrict__ attr,
    const float* __restrict__ We, const float* __restrict__ att,
    float* __restrict__ out) {
  int t = blockIdx.x * 128 + threadIdx.x;
  int i = t >> 4;  // 16 lanes per dst node, 4 dims per lane
  int g = t & 15;
  if (i >= NN) return;
  int k0 = g * 4;

  float4 W[DE];
#pragma unroll
  for (int j = 0; j < DE; ++j) W[j] = *(const float4*)(We + j * DO + k0);
  const float4 a4 = *(const float4*)(att + k0);
  float4 xri = bf4_to_f4(*(const uint2*)(xrb + (size_t)i * DO + k0));
  float4 xli = bf4_to_f4(*(const uint2*)(xlb + (size_t)i * DO + k0));

  unsigned d = cnt[i];  // same addr across 16 lanes (L1 broadcast)
  // ONE coalesced 128-B row load: up to 16 {e,src} pairs
  uint2 p = rowp[(size_t)i * ROWCAP + g];
  unsigned drow = d < ROWCAP ? d : ROWCAP;

  float4 acc = {0.f, 0.f, 0.f, 0.f};
  float den = 0.f;
  float asum = 0.f;  // lane g (g<11): sum of attr[g] over incoming edges

  // ---- main path: pairs in registers, distribute via shfl ----
  for (unsigned c = 0; c < drow; c += 8) {
    unsigned rem = drow - c;
    if (rem > 8) rem = 8;
#define LP(ii)                                                              \
    unsigned E##ii = 0u, S##ii = 0u;                                        \
    if ((unsigned)ii < rem) {                                               \
      E##ii = __shfl(p.x, (int)(c + ii), 16);                               \
      S##ii = __shfl(p.y, (int)(c + ii), 16);                               \
    }
    LP(0) LP(1) LP(2) LP(3) LP(4) LP(5) LP(6) LP(7)
#undef LP
#define LA(ii)                                                              \
    float A##ii = 0.f;                                                      \
    if ((unsigned)ii < rem && g < DE)                                       \
      A##ii = attr[(size_t)E##ii * DE + g];
    LA(0) LA(1) LA(2) LA(3) LA(4) LA(5) LA(6) LA(7)
#undef LA
#define LR(ii)                                                              \
    uint2 R##ii = {0u, 0u};                                                 \
    if ((unsigned)ii < rem) R##ii = *(const uint2*)(xlb + (size_t)S##ii * DO + k0);
    LR(0) LR(1) LR(2) LR(3) LR(4) LR(5) LR(6) LR(7)
#undef LR
#define CS(ii)                                                              \
    if ((unsigned)ii < rem) {                                               \
      float4 vl = bf4_to_f4(R##ii);                                         \
      float4 ev = {0.f, 0.f, 0.f, 0.f};                                     \
      _Pragma("unroll")                                                     \
      for (int j = 0; j < DE; ++j) {                                        \
        float a = __shfl(A##ii, j, 16);                                     \
        ev.x += a * W[j].x; ev.y += a * W[j].y;                             \
        ev.z += a * W[j].z; ev.w += a * W[j].w;                             \
      }                                                                     \
      float4 m;                                                             \
      m.x = vl.x + xri.x + ev.x; m.y = vl.y + xri.y + ev.y;                 \
      m.z = vl.z + xri.z + ev.z; m.w = vl.w + xri.w + ev.w;                 \
      m.x = m.x >= 0.f ? m.x : NEG * m.x;                                   \
      m.y = m.y >= 0.f ? m.y : NEG * m.y;                                   \
      m.z = m.z >= 0.f ? m.z : NEG * m.z;                                   \
      m.w = m.w >= 0.f ? m.w : NEG * m.w;                                   \
      float s = m.x * a4.x + m.y * a4.y + m.z * a4.z + m.w * a4.w;          \
      s += __shfl_xor(s, 1); s += __shfl_xor(s, 2);                         \
      s += __shfl_xor(s, 4); s += __shfl_xor(s, 8);                         \
      float ex = __expf(s);                                                 \
      acc.x += ex * vl.x; acc.y += ex * vl.y;                               \
      acc.z += ex * vl.z; acc.w += ex * vl.w;                               \
      den += ex;                                                            \
      asum += A##ii;                                                        \
    }
    CS(0) CS(1) CS(2) CS(3) CS(4) CS(5) CS(6) CS(7)
#undef CS
  }

  // ---- rare overflow path (d > 16) ----
  if (d > ROWCAP) {
    unsigned dtot = d < (ROWCAP + OVCAP) ? d : (ROWCAP + OVCAP);
    for (unsigned c = ROWCAP; c < dtot; c += 8) {
      unsigned rem = dtot - c;
      if (rem > 8) rem = 8;
      size_t sp = (size_t)i * OVCAP + (c - ROWCAP);
#define LQ(ii)                                                              \
      unsigned E##ii = 0u, S##ii = 0u;                                      \
      if ((unsigned)ii < rem) {                                             \
        uint2 q = ovp[sp + ii];                                             \
        E##ii = q.x; S##ii = q.y;                                           \
      }
      LQ(0) LQ(1) LQ(2) LQ(3) LQ(4) LQ(5) LQ(6) LQ(7)
#undef LQ
#define LA(ii)                                                              \
      float A##ii = 0.f;                                                    \
      if ((unsigned)ii < rem && g < DE)                                     \
        A##ii = attr[(size_t)E##ii * DE + g];
      LA(0) LA(1) LA(2) LA(3) LA(4) LA(5) LA(6) LA(7)
#undef LA
#define LR(ii)                                                              \
      uint2 R##ii = {0u, 0u};                                               \
      if ((unsigned)ii < rem) R##ii = *(const uint2*)(xlb + (size_t)S##ii * DO + k0);
      LR(0) LR(1) LR(2) LR(3) LR(4) LR(5) LR(6) LR(7)
#undef LR
#define CS(ii)                                                              \
      if ((unsigned)ii < rem) {                                             \
        float4 vl = bf4_to_f4(R##ii);                                       \
        float4 ev = {0.f, 0.f, 0.f, 0.f};                                   \
        _Pragma("unroll")                                                   \
        for (int j = 0; j < DE; ++j) {                                      \
          float a = __shfl(A##ii, j, 16);                                   \
          ev.x += a * W[j].x; ev.y += a * W[j].y;                           \
          ev.z += a * W[j].z; ev.w += a * W[j].w;                           \
        }                                                                   \
        float4 m;                                                           \
        m.x = vl.x + xri.x + ev.x; m.y = vl.y + xri.y + ev.y;               \
        m.z = vl.z + xri.z + ev.z; m.w = vl.w + xri.w + ev.w;               \
        m.x = m.x >= 0.f ? m.x : NEG * m.x;                                 \
        m.y = m.y >= 0.f ? m.y : NEG * m.y;                                 \
        m.z = m.z >= 0.f ? m.z : NEG * m.z;                                 \
        m.w = m.w >= 0.f ? m.w : NEG * m.w;                                 \
        float s = m.x * a4.x + m.y * a4.y + m.z * a4.z + m.w * a4.w;        \
        s += __shfl_xor(s, 1); s += __shfl_xor(s, 2);                       \
        s += __shfl_xor(s, 4); s += __shfl_xor(s, 8);                       \
        float ex = __expf(s);                                               \
        acc.x += ex * vl.x; acc.y += ex * vl.y;                             \
        acc.z += ex * vl.z; acc.w += ex * vl.w;                             \
        den += ex;                                                          \
        asum += A##ii;                                                      \
      }
      CS(0) CS(1) CS(2) CS(3) CS(4) CS(5) CS(6) CS(7)
#undef CS
    }
  }

  // self-loop: mean(attr)@We (linearity), shfl-broadcast from asum lanes
  float la = asum / fmaxf((float)d, 1.0f);
  float4 evs = {0.f, 0.f, 0.f, 0.f};
#pragma unroll
  for (int j = 0; j < DE; ++j) {
    float aj = __shfl(la, j, 16);
    evs.x += aj * W[j].x; evs.y += aj * W[j].y;
    evs.z += aj * W[j].z; evs.w += aj * W[j].w;
  }
  float4 m;
  m.x = xli.x + xri.x + evs.x;
  m.y = xli.y + xri.y + evs.y;
  m.z = xli.z + xri.z + evs.z;
  m.w = xli.w + xri.w + evs.w;
  m.x = m.x >= 0.f ? m.x : NEG * m.x;
  m.y = m.y >= 0.f ? m.y : NEG * m.y;
  m.z = m.z >= 0.f ? m.z : NEG * m.z;
  m.w = m.w >= 0.f ? m.w : NEG * m.w;
  float s = m.x * a4.x + m.y * a4.y + m.z * a4.z + m.w * a4.w;
  s += __shfl_xor(s, 1); s += __shfl_xor(s, 2);
  s += __shfl_xor(s, 4); s += __shfl_xor(s, 8);
  float exs = __expf(s);
  float inv = 1.0f / (den + exs);
  float4 o;
  o.x = (acc.x + exs * xli.x) * inv;
  o.y = (acc.y + exs * xli.y) * inv;
  o.z = (acc.z + exs * xli.z) * inv;
  o.w = (acc.w + exs * xli.w) * inv;
  *(float4*)(out + (size_t)i * DO + k0) = o;
}

extern "C" void kernel_launch(void* const* d_in, const int* in_sizes, int n_in,
                              void* d_out, int out_size, void* d_ws, size_t ws_size,
                              hipStream_t stream) {
  const float* x    = (const float*)d_in[0];
  const int*   ei   = (const int*)d_in[1];
  const float* attr = (const float*)d_in[2];
  const float* Wl   = (const float*)d_in[3];
  const float* Wr   = (const float*)d_in[4];
  const float* We   = (const float*)d_in[5];
  const float* att  = (const float*)d_in[6];
  float* out = (float*)d_out;

  char* ws = (char*)d_ws;
  unsigned short* xrb  = (unsigned short*)(ws + XRB_B);
  unsigned short* xlb  = (unsigned short*)(ws + XLB_B);
  uint2*          rowp = (uint2*)(ws + ROW_B);
  uint2*          ovp  = (uint2*)(ws + OV_B);
  unsigned*       cnt  = (unsigned*)(ws + CNT_B);

  hipMemsetAsync(cnt, 0, (size_t)NN * 4, stream);

  k_gemm_place<<<NBLK, 256, 0, stream>>>(
      x, Wl, Wr, ei, xlb, xrb, cnt, rowp, ovp);
  k_fused_row16<<<(NN * 16 + 127) / 128, 128, 0, stream>>>(
      xlb, xrb, rowp, ovp, cnt, attr, We, att, out);
}